// Round 10
// baseline (251.575 us; speedup 1.0000x reference)
//
#include <hip/hip_runtime.h>
#include <hip/hip_bf16.h>
#include <cstdint>

typedef __bf16 bf16x8 __attribute__((ext_vector_type(8)));
typedef __bf16 bf16x4 __attribute__((ext_vector_type(4)));
typedef short short4_ __attribute__((ext_vector_type(4)));
typedef float f32x4 __attribute__((ext_vector_type(4)));

#define SLEN 4096
#define DMODEL 1280
#define NHEADS 16
#define HD 80
#define HDP 96
#define KROW 104                 // kp row stride (elems): 208B -> conflict-free LDS reads
#define VTILE_ELEMS 3328         // v tile stride (elems): [80][40] valid + pad = 6656B
#define VTILE_LDS 3584           // LDS stride per staged v tile (7 x 1KB instrs)

#define GLD_LDS16(g, l)                                                        \
  __builtin_amdgcn_global_load_lds(                                            \
      (const __attribute__((address_space(1))) void*)(g),                      \
      (__attribute__((address_space(3))) void*)(l), 16, 0, 0)

// s_waitcnt imm (gfx9 encoding): vmcnt[3:0]|expcnt[6:4]|lgkm[11:8]|vmcnt[5:4]@14
#define WAIT_VMCNT(n) __builtin_amdgcn_s_waitcnt((n & 0xF) | 0x70 | 0xF00 | ((n >> 4) << 14))

// ---------------- fused prep: cvt hidden + transpose both weights ----------------
__device__ __forceinline__ void transpose_body(const float* __restrict__ in,
                                               __bf16* __restrict__ out,
                                               int K, int N, int bx, int by, int t) {
  __shared__ float tile[32][33];
  int n0 = bx * 32, k0 = by * 32;
  int x = t & 31, y = t >> 5;  // y in 0..7
  for (int i = 0; i < 32; i += 8)
    tile[y + i][x] = in[(size_t)(k0 + y + i) * N + n0 + x];
  __syncthreads();
  for (int i = 0; i < 32; i += 8)
    out[(size_t)(n0 + y + i) * K + k0 + x] = (__bf16)tile[x][y + i];
}

__global__ __launch_bounds__(256) void prep(const float* __restrict__ hidden,
                                            __bf16* __restrict__ hid_b,
                                            const float* __restrict__ w_qkv,
                                            __bf16* __restrict__ wqkvT,
                                            const float* __restrict__ w_proj,
                                            __bf16* __restrict__ wprojT) {
  int bid = blockIdx.x, t = threadIdx.x;
  if (bid < 5120) {
    int i = bid * 256 + t;
    float4 v = ((const float4*)hidden)[i];
    bf16x4 o = { (__bf16)v.x, (__bf16)v.y, (__bf16)v.z, (__bf16)v.w };
    ((bf16x4*)hid_b)[i] = o;
  } else if (bid < 9920) {
    int b = bid - 5120;
    transpose_body(w_qkv, wqkvT, 1280, 3840, b % 120, b / 120, t);
  } else {
    int b = bid - 9920;
    transpose_body(w_proj, wprojT, 1280, 1280, b % 40, b / 40, t);
  }
}

// ------ Big GEMM (qkv): 256x256 block, 8 waves x (128x64) wave tile -------------
// LDS-BW-bound fix: per-FLOP LDS traffic cut ~1.6x vs 64x64 wave tiles.
// 3-stage pipeline, never-drain vmcnt (waits own stage(i) only, depth-2 in flight).
// MFMA operands swapped (Bt-frag as A-operand) -> lane's 4 acc = 4 consecutive
// columns -> bf16x4 stores.
__global__ __launch_bounds__(512) void gemm_big(const __bf16* __restrict__ A,
                                                const __bf16* __restrict__ Bt,
                                                const float* __restrict__ bias,
                                                __bf16* __restrict__ C,
                                                int M, int N, int K) {
  __shared__ __attribute__((aligned(16))) __bf16 As[3][256 * 32];
  __shared__ __attribute__((aligned(16))) __bf16 Bs[3][256 * 32];

  const int t = threadIdx.x;
  const int lane = t & 63, wave = t >> 6;       // 8 waves
  const int quad = lane >> 4, l15 = lane & 15;
  const int wm = (wave & 1) * 128, wn = (wave >> 1) * 64;
  const int bm = blockIdx.x * 256, bn = blockIdx.y * 256;

  const int rs = lane >> 2, cs = (lane & 3) * 8;
  const __bf16* AgQ[2];
  const __bf16* BgQ[2];
  int aLds[2], bLds[2];
#pragma unroll
  for (int q = 0; q < 2; ++q) {
    int row = (wave * 2 + q) * 16;
    AgQ[q] = A + (size_t)(bm + row + rs) * K + cs;
    BgQ[q] = Bt + (size_t)(bn + row + rs) * K + cs;
    aLds[q] = row * 32;
    bLds[q] = row * 32;
  }

  f32x4 acc[8][4] = {};
  const int niter = K >> 5;

#pragma unroll
  for (int s = 0; s < 2; ++s) {
#pragma unroll
    for (int q = 0; q < 2; ++q) {
      GLD_LDS16(AgQ[q] + s * 32, &As[s][aLds[q]]);
      GLD_LDS16(BgQ[q] + s * 32, &Bs[s][bLds[q]]);
    }
  }

  int cmp = 0, stg = 2;
  for (int it = 0; it < niter; ++it) {
    const int kk = (it + 2 < niter ? it + 2 : niter - 1) * 32;
#pragma unroll
    for (int q = 0; q < 2; ++q) {
      GLD_LDS16(AgQ[q] + kk, &As[stg][aLds[q]]);
      GLD_LDS16(BgQ[q] + kk, &Bs[stg][bLds[q]]);
    }
    asm volatile("" ::: "memory");
    WAIT_VMCNT(8);                      // own stage(it) landed; 2 stages in flight
    __builtin_amdgcn_s_barrier();
    asm volatile("" ::: "memory");

    bf16x8 af[8], bfr[4];
#pragma unroll
    for (int i = 0; i < 8; ++i)
      af[i] = *(const bf16x8*)&As[cmp][(wm + i * 16 + l15) * 32 + quad * 8];
#pragma unroll
    for (int j = 0; j < 4; ++j)
      bfr[j] = *(const bf16x8*)&Bs[cmp][(wn + j * 16 + l15) * 32 + quad * 8];
#pragma unroll
    for (int i = 0; i < 8; ++i)
#pragma unroll
      for (int j = 0; j < 4; ++j)
        acc[i][j] = __builtin_amdgcn_mfma_f32_16x16x32_bf16(bfr[j], af[i], acc[i][j], 0, 0, 0);

    asm volatile("" ::: "memory");
    __builtin_amdgcn_s_barrier();
    asm volatile("" ::: "memory");
    cmp = (cmp == 2) ? 0 : cmp + 1;
    stg = (stg == 2) ? 0 : stg + 1;
  }

  float4 bv[4];
#pragma unroll
  for (int j = 0; j < 4; ++j)
    bv[j] = *(const float4*)&bias[bn + wn + j * 16 + quad * 4];
#pragma unroll
  for (int i = 0; i < 8; ++i) {
    size_t row = (size_t)(bm + wm + i * 16 + l15);
#pragma unroll
    for (int j = 0; j < 4; ++j) {
      int col = bn + wn + j * 16 + quad * 4;
      const float* bp = (const float*)&bv[j];
      bf16x4 ov;
#pragma unroll
      for (int r = 0; r < 4; ++r) ov[r] = (__bf16)(acc[i][j][r] + bp[r]);
      *(bf16x4*)&C[row * N + col] = ov;
    }
  }
}

// ------ GEMM (proj): 128x128 block, 4 waves, 3-stage pipeline (unchanged) ------
template <int WMW>
__global__ __launch_bounds__(WMW * 2 * 64) void gemm_bt(const __bf16* __restrict__ A,
                                                        const __bf16* __restrict__ Bt,
                                                        const float* __restrict__ bias,
                                                        void* __restrict__ C,
                                                        int M, int N, int K, int store_bf16) {
  constexpr int BM = WMW * 64;
  constexpr int NW = WMW * 2;
  constexpr int BI = 8 / NW;
  constexpr int PW = 2 + BI;
  constexpr int ASZ = BM * 32, BSZ = 128 * 32;

  __shared__ __attribute__((aligned(16))) __bf16 As[3][ASZ];
  __shared__ __attribute__((aligned(16))) __bf16 Bs[3][BSZ];

  const int t = threadIdx.x;
  const int lane = t & 63, wave = t >> 6;
  const int quad = lane >> 4, l15 = lane & 15;
  const int wm = (wave & (WMW - 1)) * 64, wn = (wave / WMW) * 64;
  const int bm = blockIdx.x * BM, bn = blockIdx.y * 128;

  const int rs = lane >> 2, cs = (lane & 3) * 8;
  const __bf16* AgQ[2];
  const __bf16* BgQ[BI];
  int aLds[2], bLds[BI];
#pragma unroll
  for (int q = 0; q < 2; ++q) {
    int row = (wave * 2 + q) * 16;
    AgQ[q] = A + (size_t)(bm + row + rs) * K + cs;
    aLds[q] = row * 32;
  }
#pragma unroll
  for (int q = 0; q < BI; ++q) {
    int row = (wave * BI + q) * 16;
    BgQ[q] = Bt + (size_t)(bn + row + rs) * K + cs;
    bLds[q] = row * 32;
  }

  f32x4 acc[4][4] = {};
  const int niter = K >> 5;

#pragma unroll
  for (int s = 0; s < 2; ++s) {
#pragma unroll
    for (int q = 0; q < 2; ++q) GLD_LDS16(AgQ[q] + s * 32, &As[s][aLds[q]]);
#pragma unroll
    for (int q = 0; q < BI; ++q) GLD_LDS16(BgQ[q] + s * 32, &Bs[s][bLds[q]]);
  }

  int cmp = 0, stg = 2;
  for (int it = 0; it < niter; ++it) {
    const int kk = (it + 2 < niter ? it + 2 : niter - 1) * 32;
#pragma unroll
    for (int q = 0; q < 2; ++q) GLD_LDS16(AgQ[q] + kk, &As[stg][aLds[q]]);
#pragma unroll
    for (int q = 0; q < BI; ++q) GLD_LDS16(BgQ[q] + kk, &Bs[stg][bLds[q]]);
    asm volatile("" ::: "memory");
    WAIT_VMCNT(2 * PW);
    __builtin_amdgcn_s_barrier();
    asm volatile("" ::: "memory");

    bf16x8 af[4], bfr[4];
#pragma unroll
    for (int i = 0; i < 4; ++i)
      af[i] = *(const bf16x8*)&As[cmp][(wm + i * 16 + l15) * 32 + quad * 8];
#pragma unroll
    for (int j = 0; j < 4; ++j)
      bfr[j] = *(const bf16x8*)&Bs[cmp][(wn + j * 16 + l15) * 32 + quad * 8];
#pragma unroll
    for (int i = 0; i < 4; ++i)
#pragma unroll
      for (int j = 0; j < 4; ++j)
        acc[i][j] = __builtin_amdgcn_mfma_f32_16x16x32_bf16(bfr[j], af[i], acc[i][j], 0, 0, 0);

    asm volatile("" ::: "memory");
    __builtin_amdgcn_s_barrier();
    asm volatile("" ::: "memory");
    cmp = (cmp == 2) ? 0 : cmp + 1;
    stg = (stg == 2) ? 0 : stg + 1;
  }

  float4 bv[4];
#pragma unroll
  for (int j = 0; j < 4; ++j)
    bv[j] = *(const float4*)&bias[bn + wn + j * 16 + quad * 4];
#pragma unroll
  for (int i = 0; i < 4; ++i) {
    size_t row = (size_t)(bm + wm + i * 16 + l15);
#pragma unroll
    for (int j = 0; j < 4; ++j) {
      int col = bn + wn + j * 16 + quad * 4;
      const float* bp = (const float*)&bv[j];
      if (store_bf16) {
        bf16x4 ov;
#pragma unroll
        for (int r = 0; r < 4; ++r) ov[r] = (__bf16)(acc[i][j][r] + bp[r]);
        *(bf16x4*)&((__bf16*)C)[row * N + col] = ov;
      } else {
        float4 fv;
        fv.x = acc[i][j][0] + bp[0];
        fv.y = acc[i][j][1] + bp[1];
        fv.z = acc[i][j][2] + bp[2];
        fv.w = acc[i][j][3] + bp[3];
        *(float4*)&((float*)C)[row * N + col] = fv;
      }
    }
  }
}

// --- RoPE q,k + pack (vectorized b128 loads/stores) ---
__global__ __launch_bounds__(256) void rope_pack(const __bf16* __restrict__ qkv,
                                                 const float* __restrict__ freqs,
                                                 __bf16* __restrict__ qp,
                                                 __bf16* __restrict__ kp,
                                                 __bf16* __restrict__ vt) {
  const float QSCALE = 0.11180339887498949f * 1.44269504088896340f;
  int h = blockIdx.y;
  int s0 = blockIdx.x * 64;
  int t = threadIdx.x;
  int sp = t >> 2, l4 = t & 3;
  int s = s0 + sp;
  const __bf16* row = qkv + (size_t)s * 3840 + h * 80;
  __bf16* qo = qp + (size_t)(h * SLEN + s) * HDP;
  __bf16* ko = kp + (size_t)(h * SLEN + s) * KROW;

  __shared__ float vtile[64][81];

  for (int c = l4; c < 10; c += 4) {
    int base = (c < 5) ? c * 8 : (c - 5) * 8;
    bf16x8 xa = *(const bf16x8*)(row + base);
    bf16x8 xb = *(const bf16x8*)(row + base + 40);
    bf16x8 ya = *(const bf16x8*)(row + 1280 + base);
    bf16x8 yb = *(const bf16x8*)(row + 1280 + base + 40);
    float4 f0 = *(const float4*)(freqs + s * 40 + base);
    float4 f1 = *(const float4*)(freqs + s * 40 + base + 4);
    float fr[8] = {f0.x, f0.y, f0.z, f0.w, f1.x, f1.y, f1.z, f1.w};
    bf16x8 qv, kv;
#pragma unroll
    for (int e = 0; e < 8; ++e) {
      float cs = __builtin_cosf(fr[e]), sn = __builtin_sinf(fr[e]);
      float x1 = (float)xa[e], x2 = (float)xb[e];
      float y1 = (float)ya[e], y2 = (float)yb[e];
      float qvv, kvv;
      if (c < 5) { qvv = x1 * cs - x2 * sn; kvv = y1 * cs - y2 * sn; }
      else       { qvv = x1 * sn + x2 * cs; kvv = y1 * sn + y2 * cs; }
      qv[e] = (__bf16)(qvv * QSCALE);
      kv[e] = (__bf16)kvv;
    }
    *(bf16x8*)(qo + c * 8) = qv;
    *(bf16x8*)(ko + c * 8) = kv;
  }
  {
    bf16x8 z = {};
    if (l4 == 0) *(bf16x8*)(qo + 80) = z;
    if (l4 == 1) *(bf16x8*)(qo + 88) = z;
    if (l4 == 2) *(bf16x8*)(ko + 80) = z;
    if (l4 == 3) *(bf16x8*)(ko + 88) = z;
  }

  for (int c = l4; c < 10; c += 4) {
    bf16x8 v = *(const bf16x8*)(row + 2560 + c * 8);
#pragma unroll
    for (int e = 0; e < 8; ++e)
      vtile[sp][c * 8 + e] = (float)v[e];
  }
  __syncthreads();

  for (int idx = t; idx < 640; idx += 256) {
    int c2 = idx >= 320;
    int rem = idx - (c2 ? 320 : 0);
    int d = rem >> 2, kc = rem & 3;
    __bf16* tb = vt + (size_t)(h * (SLEN / 32) + (s0 >> 5) + c2) * VTILE_ELEMS;
    bf16x8 ov;
#pragma unroll
    for (int r = 0; r < 4; ++r) {
      ov[r]     = (__bf16)vtile[c2 * 32 + kc * 4 + r][d];
      ov[r + 4] = (__bf16)vtile[c2 * 32 + 16 + kc * 4 + r][d];
    }
    *(bf16x8*)(tb + d * 40 + kc * 8) = ov;
  }
}

// ----------------- flash attention: 32 q-rows/wave, b128 V reads -----------------
__global__ __launch_bounds__(256) void flash_attn(const __bf16* __restrict__ qp,
                                                  const __bf16* __restrict__ kp,
                                                  const __bf16* __restrict__ vt,
                                                  const int* __restrict__ cu, int nseg,
                                                  __bf16* __restrict__ out) {
  const float MEXP = 16.0f;
  int h = blockIdx.y;
  int q0 = blockIdx.x * 128;
  int seg = 0;
  for (int i = 1; i < nseg; ++i)
    if (cu[i] <= q0) seg = i;
  int kstart = cu[seg], kend = cu[seg + 1];

  int t = threadIdx.x;
  int lane = t & 63, wave = t >> 6;
  int quad = lane >> 4, l15 = lane & 15;

  __shared__ __attribute__((aligned(16))) __bf16 Ks[2][64 * KROW];
  __shared__ __attribute__((aligned(16))) __bf16 Vs[2][2 * VTILE_LDS];

  bf16x8 qf[2][3];
#pragma unroll
  for (int qs = 0; qs < 2; ++qs) {
    const __bf16* qptr = qp + (size_t)(h * SLEN + q0 + wave * 32 + qs * 16 + l15) * HDP + quad * 8;
    qf[qs][0] = *(const bf16x8*)(qptr);
    qf[qs][1] = *(const bf16x8*)(qptr + 32);
    qf[qs][2] = *(const bf16x8*)(qptr + 64);
  }

  f32x4 o[2][5] = {};
  float l_p[2] = {0.f, 0.f};

  const __bf16* gK = kp + (size_t)(h * SLEN + kstart) * KROW + lane * 8;
  const __bf16* gV = vt + (size_t)(h * (SLEN / 32) + (kstart >> 5)) * VTILE_ELEMS + lane * 8;

  const int niter = (kend - kstart) >> 6;

  auto stage = [&](int kn, int buf) {
    const __bf16* ksrc = gK + (size_t)kn * (64 * KROW);
    const __bf16* vsrc = gV + (size_t)kn * (2 * VTILE_ELEMS);
#pragma unroll
    for (int i0 = 0; i0 < 7; ++i0) {
      int i = wave * 7 + i0;
      int ii = i < 27 ? i : 26;
      if (ii < 13)
        GLD_LDS16(ksrc + ii * 512, &Ks[buf][ii * 512]);
      else if (ii < 20)
        GLD_LDS16(vsrc + (ii - 13) * 512, &Vs[buf][(ii - 13) * 512]);
      else
        GLD_LDS16(vsrc + VTILE_ELEMS + (ii - 20) * 512, &Vs[buf][VTILE_LDS + (ii - 20) * 512]);
    }
  };

  stage(0, 0);

  for (int it = 0; it < niter; ++it) {
    const int cur = it & 1, nxt = cur ^ 1;
    const int kn = (it + 1 < niter) ? it + 1 : niter - 1;
    stage(kn, nxt);
    asm volatile("" ::: "memory");
    WAIT_VMCNT(7);
    __builtin_amdgcn_s_barrier();
    asm volatile("" ::: "memory");

    f32x4 sc[2][4];
#pragma unroll
    for (int nt = 0; nt < 4; ++nt) {
      sc[0][nt] = f32x4{-MEXP, -MEXP, -MEXP, -MEXP};
      sc[1][nt] = sc[0][nt];
#pragma unroll
      for (int c = 0; c < 3; ++c) {
        bf16x8 kf = *(const bf16x8*)&Ks[cur][(nt * 16 + l15) * KROW + quad * 8 + c * 32];
        sc[0][nt] = __builtin_amdgcn_mfma_f32_16x16x32_bf16(kf, qf[0][c], sc[0][nt], 0, 0, 0);
        sc[1][nt] = __builtin_amdgcn_mfma_f32_16x16x32_bf16(kf, qf[1][c], sc[1][nt], 0, 0, 0);
      }
    }

    bf16x4 pf[2][4];
#pragma unroll
    for (int qs = 0; qs < 2; ++qs)
#pragma unroll
      for (int nt = 0; nt < 4; ++nt)
#pragma unroll
        for (int r = 0; r < 4; ++r) {
          float p = __builtin_amdgcn_exp2f(sc[qs][nt][r]);
          l_p[qs] += p;
          pf[qs][nt][r] = (__bf16)p;
        }

#pragma unroll
    for (int g = 0; g < 2; ++g) {
#pragma unroll
      for (int dt = 0; dt < 5; ++dt) {
        bf16x8 vv = *(const bf16x8*)&Vs[cur][g * VTILE_LDS + (dt * 16 + l15) * 40 + quad * 8];
        bf16x4 vlo = __builtin_shufflevector(vv, vv, 0, 1, 2, 3);
        bf16x4 vhi = __builtin_shufflevector(vv, vv, 4, 5, 6, 7);
#pragma unroll
        for (int qs = 0; qs < 2; ++qs) {
          o[qs][dt] = __builtin_amdgcn_mfma_f32_16x16x16bf16_1k(
              *(short4_*)&vlo, *(short4_*)&pf[qs][g * 2], o[qs][dt], 0, 0, 0);
          o[qs][dt] = __builtin_amdgcn_mfma_f32_16x16x16bf16_1k(
              *(short4_*)&vhi, *(short4_*)&pf[qs][g * 2 + 1], o[qs][dt], 0, 0, 0);
        }
      }
    }

    asm volatile("" ::: "memory");
    __builtin_amdgcn_s_barrier();
    asm volatile("" ::: "memory");
  }

#pragma unroll
  for (int qs = 0; qs < 2; ++qs) {
    float l = l_p[qs];
    l += __shfl_xor(l, 16);
    l += __shfl_xor(l, 32);
    float rinv = 1.0f / l;
    int qrow = q0 + wave * 32 + qs * 16 + l15;
#pragma unroll
    for (int dt = 0; dt < 5; ++dt) {
      bf16x4 ov;
#pragma unroll
      for (int r = 0; r < 4; ++r)
        ov[r] = (__bf16)(o[qs][dt][r] * rinv);
      *(bf16x4*)&out[(size_t)qrow * DMODEL + h * 80 + dt * 16 + quad * 4] = ov;
    }
  }
}

extern "C" void kernel_launch(void* const* d_in, const int* in_sizes, int n_in,
                              void* d_out, int out_size, void* d_ws, size_t ws_size,
                              hipStream_t stream) {
  const float* hidden = (const float*)d_in[0];
  const int* cu       = (const int*)d_in[1];
  const float* freqs  = (const float*)d_in[2];
  const float* w_qkv  = (const float*)d_in[3];
  const float* b_qkv  = (const float*)d_in[4];
  const float* w_proj = (const float*)d_in[5];
  const float* b_proj = (const float*)d_in[6];
  float* out = (float*)d_out;

  char* ws = (char*)d_ws;
  size_t off = 0;
  auto alloc = [&](size_t bytes) {
    char* p = ws + off;
    off += (bytes + 255) & ~(size_t)255;
    return p;
  };
  __bf16* hid_b  = (__bf16*)alloc((size_t)SLEN * DMODEL * 2);
  __bf16* wqkvT  = (__bf16*)alloc((size_t)3840 * 1280 * 2);
  __bf16* wprojT = (__bf16*)alloc((size_t)1280 * 1280 * 2);
  __bf16* qkvb   = (__bf16*)alloc((size_t)SLEN * 3840 * 2);
  __bf16* qp     = (__bf16*)alloc((size_t)NHEADS * SLEN * HDP * 2);
  __bf16* kp     = (__bf16*)alloc((size_t)NHEADS * SLEN * KROW * 2 + 1024);
  __bf16* vt     = (__bf16*)alloc((size_t)NHEADS * (SLEN / 32) * VTILE_ELEMS * 2 + 1024);
  __bf16* attn   = hid_b;  // alias: hid_b dead after qkv GEMM

  prep<<<11520, 256, 0, stream>>>(hidden, hid_b, w_qkv, wqkvT, w_proj, wprojT);
  gemm_big<<<dim3(SLEN / 256, 3840 / 256), 512, 0, stream>>>(hid_b, wqkvT, b_qkv, qkvb,
                                                             SLEN, 3840, 1280);
  rope_pack<<<dim3(SLEN / 64, NHEADS), 256, 0, stream>>>(qkvb, freqs, qp, kp, vt);
  int nseg = in_sizes[1] - 1;
  flash_attn<<<dim3(SLEN / 128, NHEADS), 256, 0, stream>>>(qp, kp, vt, cu, nseg, attn);
  gemm_bt<2><<<dim3(SLEN / 128, DMODEL / 128), 256, 0, stream>>>(attn, wprojT, b_proj, out,
                                                                 SLEN, DMODEL, 1280, 0);
}

// Round 11
// 244.067 us; speedup vs baseline: 1.0308x; 1.0308x over previous
//
#include <hip/hip_runtime.h>
#include <hip/hip_bf16.h>
#include <cstdint>

typedef __bf16 bf16x8 __attribute__((ext_vector_type(8)));
typedef __bf16 bf16x4 __attribute__((ext_vector_type(4)));
typedef short short4_ __attribute__((ext_vector_type(4)));
typedef float f32x4 __attribute__((ext_vector_type(4)));

#define SLEN 4096
#define DMODEL 1280
#define NHEADS 16
#define HD 80
#define HDP 96                   // q/k row stride (192B; 2-way LDS alias = free)
#define VTILE_ELEMS 3328         // v tile stride (elems): [80][40] valid + pad = 6656B
#define VTILE_LDS 3584           // LDS stride per staged v tile (7 x 1KB instrs)

#define GLD_LDS16(g, l)                                                        \
  __builtin_amdgcn_global_load_lds(                                            \
      (const __attribute__((address_space(1))) void*)(g),                      \
      (__attribute__((address_space(3))) void*)(l), 16, 0, 0)

// s_waitcnt imm (gfx9 encoding): vmcnt[3:0]|expcnt[6:4]|lgkm[11:8]|vmcnt[5:4]@14
#define WAIT_VMCNT(n) __builtin_amdgcn_s_waitcnt((n & 0xF) | 0x70 | 0xF00 | ((n >> 4) << 14))

// ---------------- fused prep: cvt hidden + transpose both weights ----------------
__device__ __forceinline__ void transpose_body(const float* __restrict__ in,
                                               __bf16* __restrict__ out,
                                               int K, int N, int bx, int by, int t) {
  __shared__ float tile[32][33];
  int n0 = bx * 32, k0 = by * 32;
  int x = t & 31, y = t >> 5;  // y in 0..7
  for (int i = 0; i < 32; i += 8)
    tile[y + i][x] = in[(size_t)(k0 + y + i) * N + n0 + x];
  __syncthreads();
  for (int i = 0; i < 32; i += 8)
    out[(size_t)(n0 + y + i) * K + k0 + x] = (__bf16)tile[x][y + i];
}

__global__ __launch_bounds__(256) void prep(const float* __restrict__ hidden,
                                            __bf16* __restrict__ hid_b,
                                            const float* __restrict__ w_qkv,
                                            __bf16* __restrict__ wqkvT,
                                            const float* __restrict__ w_proj,
                                            __bf16* __restrict__ wprojT) {
  int bid = blockIdx.x, t = threadIdx.x;
  if (bid < 5120) {
    int i = bid * 256 + t;
    float4 v = ((const float4*)hidden)[i];
    bf16x4 o = { (__bf16)v.x, (__bf16)v.y, (__bf16)v.z, (__bf16)v.w };
    ((bf16x4*)hid_b)[i] = o;
  } else if (bid < 9920) {
    int b = bid - 5120;
    transpose_body(w_qkv, wqkvT, 1280, 3840, b % 120, b / 120, t);
  } else {
    int b = bid - 9920;
    transpose_body(w_proj, wprojT, 1280, 1280, b % 40, b / 40, t);
  }
}

// ------ GEMM: C(M,N) = A(M,K) * Bt(N,K)^T + bias, 3-stage pipeline ------
// WMW=4: 256x128 block, 8 waves, 73728B LDS -> 2 blocks/CU (the measured
// local optimum; 256x256 at 1 block/CU regressed -- occupancy cliff).
// MFMA operands swapped (Bt as A-operand): lane's 4 acc = 4 consecutive
// columns -> vectorized stores.
template <int WMW>
__global__ __launch_bounds__(WMW * 2 * 64) void gemm_bt(const __bf16* __restrict__ A,
                                                        const __bf16* __restrict__ Bt,
                                                        const float* __restrict__ bias,
                                                        void* __restrict__ C,
                                                        int M, int N, int K, int store_bf16) {
  constexpr int BM = WMW * 64;
  constexpr int NW = WMW * 2;
  constexpr int BI = 8 / NW;
  constexpr int PW = 2 + BI;
  constexpr int ASZ = BM * 32, BSZ = 128 * 32;

  __shared__ __attribute__((aligned(16))) __bf16 As[3][ASZ];
  __shared__ __attribute__((aligned(16))) __bf16 Bs[3][BSZ];

  const int t = threadIdx.x;
  const int lane = t & 63, wave = t >> 6;
  const int quad = lane >> 4, l15 = lane & 15;
  const int wm = (wave & (WMW - 1)) * 64, wn = (wave / WMW) * 64;
  const int bm = blockIdx.x * BM, bn = blockIdx.y * 128;

  const int rs = lane >> 2, cs = (lane & 3) * 8;
  const __bf16* AgQ[2];
  const __bf16* BgQ[BI];
  int aLds[2], bLds[BI];
#pragma unroll
  for (int q = 0; q < 2; ++q) {
    int row = (wave * 2 + q) * 16;
    AgQ[q] = A + (size_t)(bm + row + rs) * K + cs;
    aLds[q] = row * 32;
  }
#pragma unroll
  for (int q = 0; q < BI; ++q) {
    int row = (wave * BI + q) * 16;
    BgQ[q] = Bt + (size_t)(bn + row + rs) * K + cs;
    bLds[q] = row * 32;
  }

  f32x4 acc[4][4] = {};
  const int niter = K >> 5;

#pragma unroll
  for (int s = 0; s < 2; ++s) {
#pragma unroll
    for (int q = 0; q < 2; ++q) GLD_LDS16(AgQ[q] + s * 32, &As[s][aLds[q]]);
#pragma unroll
    for (int q = 0; q < BI; ++q) GLD_LDS16(BgQ[q] + s * 32, &Bs[s][bLds[q]]);
  }

  int cmp = 0, stg = 2;
  for (int it = 0; it < niter; ++it) {
    const int kk = (it + 2 < niter ? it + 2 : niter - 1) * 32;
#pragma unroll
    for (int q = 0; q < 2; ++q) GLD_LDS16(AgQ[q] + kk, &As[stg][aLds[q]]);
#pragma unroll
    for (int q = 0; q < BI; ++q) GLD_LDS16(BgQ[q] + kk, &Bs[stg][bLds[q]]);
    asm volatile("" ::: "memory");
    WAIT_VMCNT(2 * PW);
    __builtin_amdgcn_s_barrier();
    asm volatile("" ::: "memory");

    bf16x8 af[4], bfr[4];
#pragma unroll
    for (int i = 0; i < 4; ++i)
      af[i] = *(const bf16x8*)&As[cmp][(wm + i * 16 + l15) * 32 + quad * 8];
#pragma unroll
    for (int j = 0; j < 4; ++j)
      bfr[j] = *(const bf16x8*)&Bs[cmp][(wn + j * 16 + l15) * 32 + quad * 8];
#pragma unroll
    for (int i = 0; i < 4; ++i)
#pragma unroll
      for (int j = 0; j < 4; ++j)
        acc[i][j] = __builtin_amdgcn_mfma_f32_16x16x32_bf16(bfr[j], af[i], acc[i][j], 0, 0, 0);

    asm volatile("" ::: "memory");
    __builtin_amdgcn_s_barrier();
    asm volatile("" ::: "memory");
    cmp = (cmp == 2) ? 0 : cmp + 1;
    stg = (stg == 2) ? 0 : stg + 1;
  }

  float4 bv[4];
#pragma unroll
  for (int j = 0; j < 4; ++j)
    bv[j] = *(const float4*)&bias[bn + wn + j * 16 + quad * 4];
#pragma unroll
  for (int i = 0; i < 4; ++i) {
    size_t row = (size_t)(bm + wm + i * 16 + l15);
#pragma unroll
    for (int j = 0; j < 4; ++j) {
      int col = bn + wn + j * 16 + quad * 4;
      const float* bp = (const float*)&bv[j];
      if (store_bf16) {
        bf16x4 ov;
#pragma unroll
        for (int r = 0; r < 4; ++r) ov[r] = (__bf16)(acc[i][j][r] + bp[r]);
        *(bf16x4*)&((__bf16*)C)[row * N + col] = ov;
      } else {
        float4 fv;
        fv.x = acc[i][j][0] + bp[0];
        fv.y = acc[i][j][1] + bp[1];
        fv.z = acc[i][j][2] + bp[2];
        fv.w = acc[i][j][3] + bp[3];
        *(float4*)&((float*)C)[row * N + col] = fv;
      }
    }
  }
}

// --- RoPE q,k + pack (vectorized b128 loads/stores):
//   qp, kp: (H, S, 96), d 80..95 zero; q pre-scaled by log2e/sqrt(80)
//   vt: per-head, per-32-key tiles [80 d][40 pos], KEY-PERMUTED:
//       pos = q4*8 + sub*4 + r  <->  key = sub*16 + q4*4 + r
__global__ __launch_bounds__(256) void rope_pack(const __bf16* __restrict__ qkv,
                                                 const float* __restrict__ freqs,
                                                 __bf16* __restrict__ qp,
                                                 __bf16* __restrict__ kp,
                                                 __bf16* __restrict__ vt) {
  const float QSCALE = 0.11180339887498949f * 1.44269504088896340f;
  int h = blockIdx.y;
  int s0 = blockIdx.x * 64;
  int t = threadIdx.x;
  int sp = t >> 2, l4 = t & 3;
  int s = s0 + sp;
  const __bf16* row = qkv + (size_t)s * 3840 + h * 80;
  __bf16* qo = qp + (size_t)(h * SLEN + s) * HDP;
  __bf16* ko = kp + (size_t)(h * SLEN + s) * HDP;

  __shared__ float vtile[64][81];

  for (int c = l4; c < 10; c += 4) {
    int base = (c < 5) ? c * 8 : (c - 5) * 8;
    bf16x8 xa = *(const bf16x8*)(row + base);
    bf16x8 xb = *(const bf16x8*)(row + base + 40);
    bf16x8 ya = *(const bf16x8*)(row + 1280 + base);
    bf16x8 yb = *(const bf16x8*)(row + 1280 + base + 40);
    float4 f0 = *(const float4*)(freqs + s * 40 + base);
    float4 f1 = *(const float4*)(freqs + s * 40 + base + 4);
    float fr[8] = {f0.x, f0.y, f0.z, f0.w, f1.x, f1.y, f1.z, f1.w};
    bf16x8 qv, kv;
#pragma unroll
    for (int e = 0; e < 8; ++e) {
      float cs = __builtin_cosf(fr[e]), sn = __builtin_sinf(fr[e]);
      float x1 = (float)xa[e], x2 = (float)xb[e];
      float y1 = (float)ya[e], y2 = (float)yb[e];
      float qvv, kvv;
      if (c < 5) { qvv = x1 * cs - x2 * sn; kvv = y1 * cs - y2 * sn; }
      else       { qvv = x1 * sn + x2 * cs; kvv = y1 * sn + y2 * cs; }
      qv[e] = (__bf16)(qvv * QSCALE);
      kv[e] = (__bf16)kvv;
    }
    *(bf16x8*)(qo + c * 8) = qv;
    *(bf16x8*)(ko + c * 8) = kv;
  }
  {
    bf16x8 z = {};
    if (l4 == 0) *(bf16x8*)(qo + 80) = z;
    if (l4 == 1) *(bf16x8*)(qo + 88) = z;
    if (l4 == 2) *(bf16x8*)(ko + 80) = z;
    if (l4 == 3) *(bf16x8*)(ko + 88) = z;
  }

  for (int c = l4; c < 10; c += 4) {
    bf16x8 v = *(const bf16x8*)(row + 2560 + c * 8);
#pragma unroll
    for (int e = 0; e < 8; ++e)
      vtile[sp][c * 8 + e] = (float)v[e];
  }
  __syncthreads();

  for (int idx = t; idx < 640; idx += 256) {
    int c2 = idx >= 320;
    int rem = idx - (c2 ? 320 : 0);
    int d = rem >> 2, kc = rem & 3;
    __bf16* tb = vt + (size_t)(h * (SLEN / 32) + (s0 >> 5) + c2) * VTILE_ELEMS;
    bf16x8 ov;
#pragma unroll
    for (int r = 0; r < 4; ++r) {
      ov[r]     = (__bf16)vtile[c2 * 32 + kc * 4 + r][d];
      ov[r + 4] = (__bf16)vtile[c2 * 32 + 16 + kc * 4 + r][d];
    }
    *(bf16x8*)(tb + d * 40 + kc * 8) = ov;
  }
}

// ----------------- flash attention: 32 q-rows/wave, b128 V reads -----------------
// KROW=96 now (2-way LDS alias free per m136): K staging 12 instrs/tile,
// LDS 53248B. Stage slots: 12 K + 7 V0 + 7 V1 = 26 real, 2 dummies; 7/wave.
__global__ __launch_bounds__(256) void flash_attn(const __bf16* __restrict__ qp,
                                                  const __bf16* __restrict__ kp,
                                                  const __bf16* __restrict__ vt,
                                                  const int* __restrict__ cu, int nseg,
                                                  __bf16* __restrict__ out) {
  const float MEXP = 16.0f;
  int h = blockIdx.y;
  int q0 = blockIdx.x * 128;
  int seg = 0;
  for (int i = 1; i < nseg; ++i)
    if (cu[i] <= q0) seg = i;
  int kstart = cu[seg], kend = cu[seg + 1];

  int t = threadIdx.x;
  int lane = t & 63, wave = t >> 6;
  int quad = lane >> 4, l15 = lane & 15;

  __shared__ __attribute__((aligned(16))) __bf16 Ks[2][64 * HDP];       // 2x12288 B
  __shared__ __attribute__((aligned(16))) __bf16 Vs[2][2 * VTILE_LDS];  // 2x14336 B

  bf16x8 qf[2][3];
#pragma unroll
  for (int qs = 0; qs < 2; ++qs) {
    const __bf16* qptr = qp + (size_t)(h * SLEN + q0 + wave * 32 + qs * 16 + l15) * HDP + quad * 8;
    qf[qs][0] = *(const bf16x8*)(qptr);
    qf[qs][1] = *(const bf16x8*)(qptr + 32);
    qf[qs][2] = *(const bf16x8*)(qptr + 64);
  }

  f32x4 o[2][5] = {};
  float l_p[2] = {0.f, 0.f};

  const __bf16* gK = kp + (size_t)(h * SLEN + kstart) * HDP + lane * 8;
  const __bf16* gV = vt + (size_t)(h * (SLEN / 32) + (kstart >> 5)) * VTILE_ELEMS + lane * 8;

  const int niter = (kend - kstart) >> 6;

  auto stage = [&](int kn, int buf) {
    const __bf16* ksrc = gK + (size_t)kn * (64 * HDP);
    const __bf16* vsrc = gV + (size_t)kn * (2 * VTILE_ELEMS);
#pragma unroll
    for (int i0 = 0; i0 < 7; ++i0) {
      int i = wave * 7 + i0;
      int ii = i < 26 ? i : 25;   // dummies re-issue slot 25 (idempotent)
      if (ii < 12)
        GLD_LDS16(ksrc + ii * 512, &Ks[buf][ii * 512]);
      else if (ii < 19)
        GLD_LDS16(vsrc + (ii - 12) * 512, &Vs[buf][(ii - 12) * 512]);
      else
        GLD_LDS16(vsrc + VTILE_ELEMS + (ii - 19) * 512, &Vs[buf][VTILE_LDS + (ii - 19) * 512]);
    }
  };

  stage(0, 0);

  for (int it = 0; it < niter; ++it) {
    const int cur = it & 1, nxt = cur ^ 1;
    const int kn = (it + 1 < niter) ? it + 1 : niter - 1;
    stage(kn, nxt);
    asm volatile("" ::: "memory");
    WAIT_VMCNT(7);
    __builtin_amdgcn_s_barrier();
    asm volatile("" ::: "memory");

    f32x4 sc[2][4];
#pragma unroll
    for (int nt = 0; nt < 4; ++nt) {
      sc[0][nt] = f32x4{-MEXP, -MEXP, -MEXP, -MEXP};
      sc[1][nt] = sc[0][nt];
#pragma unroll
      for (int c = 0; c < 3; ++c) {
        bf16x8 kf = *(const bf16x8*)&Ks[cur][(nt * 16 + l15) * HDP + quad * 8 + c * 32];
        sc[0][nt] = __builtin_amdgcn_mfma_f32_16x16x32_bf16(kf, qf[0][c], sc[0][nt], 0, 0, 0);
        sc[1][nt] = __builtin_amdgcn_mfma_f32_16x16x32_bf16(kf, qf[1][c], sc[1][nt], 0, 0, 0);
      }
    }

    bf16x4 pf[2][4];
#pragma unroll
    for (int qs = 0; qs < 2; ++qs)
#pragma unroll
      for (int nt = 0; nt < 4; ++nt)
#pragma unroll
        for (int r = 0; r < 4; ++r) {
          float p = __builtin_amdgcn_exp2f(sc[qs][nt][r]);
          l_p[qs] += p;
          pf[qs][nt][r] = (__bf16)p;
        }

#pragma unroll
    for (int g = 0; g < 2; ++g) {
#pragma unroll
      for (int dt = 0; dt < 5; ++dt) {
        bf16x8 vv = *(const bf16x8*)&Vs[cur][g * VTILE_LDS + (dt * 16 + l15) * 40 + quad * 8];
        bf16x4 vlo = __builtin_shufflevector(vv, vv, 0, 1, 2, 3);
        bf16x4 vhi = __builtin_shufflevector(vv, vv, 4, 5, 6, 7);
#pragma unroll
        for (int qs = 0; qs < 2; ++qs) {
          o[qs][dt] = __builtin_amdgcn_mfma_f32_16x16x16bf16_1k(
              *(short4_*)&vlo, *(short4_*)&pf[qs][g * 2], o[qs][dt], 0, 0, 0);
          o[qs][dt] = __builtin_amdgcn_mfma_f32_16x16x16bf16_1k(
              *(short4_*)&vhi, *(short4_*)&pf[qs][g * 2 + 1], o[qs][dt], 0, 0, 0);
        }
      }
    }

    asm volatile("" ::: "memory");
    __builtin_amdgcn_s_barrier();
    asm volatile("" ::: "memory");
  }

#pragma unroll
  for (int qs = 0; qs < 2; ++qs) {
    float l = l_p[qs];
    l += __shfl_xor(l, 16);
    l += __shfl_xor(l, 32);
    float rinv = 1.0f / l;
    int qrow = q0 + wave * 32 + qs * 16 + l15;
#pragma unroll
    for (int dt = 0; dt < 5; ++dt) {
      bf16x4 ov;
#pragma unroll
      for (int r = 0; r < 4; ++r)
        ov[r] = (__bf16)(o[qs][dt][r] * rinv);
      *(bf16x4*)&out[(size_t)qrow * DMODEL + h * 80 + dt * 16 + quad * 4] = ov;
    }
  }
}

extern "C" void kernel_launch(void* const* d_in, const int* in_sizes, int n_in,
                              void* d_out, int out_size, void* d_ws, size_t ws_size,
                              hipStream_t stream) {
  const float* hidden = (const float*)d_in[0];
  const int* cu       = (const int*)d_in[1];
  const float* freqs  = (const float*)d_in[2];
  const float* w_qkv  = (const float*)d_in[3];
  const float* b_qkv  = (const float*)d_in[4];
  const float* w_proj = (const float*)d_in[5];
  const float* b_proj = (const float*)d_in[6];
  float* out = (float*)d_out;

  char* ws = (char*)d_ws;
  size_t off = 0;
  auto alloc = [&](size_t bytes) {
    char* p = ws + off;
    off += (bytes + 255) & ~(size_t)255;
    return p;
  };
  __bf16* hid_b  = (__bf16*)alloc((size_t)SLEN * DMODEL * 2);
  __bf16* wqkvT  = (__bf16*)alloc((size_t)3840 * 1280 * 2);
  __bf16* wprojT = (__bf16*)alloc((size_t)1280 * 1280 * 2);
  __bf16* qkvb   = (__bf16*)alloc((size_t)SLEN * 3840 * 2);
  __bf16* qp     = (__bf16*)alloc((size_t)NHEADS * SLEN * HDP * 2);
  __bf16* kp     = (__bf16*)alloc((size_t)NHEADS * SLEN * HDP * 2 + 1024);
  __bf16* vt     = (__bf16*)alloc((size_t)NHEADS * (SLEN / 32) * VTILE_ELEMS * 2 + 1024);
  __bf16* attn   = hid_b;  // alias: hid_b dead after qkv GEMM

  prep<<<11520, 256, 0, stream>>>(hidden, hid_b, w_qkv, wqkvT, w_proj, wprojT);
  gemm_bt<4><<<dim3(SLEN / 256, 3840 / 128), 512, 0, stream>>>(hid_b, wqkvT, b_qkv, qkvb,
                                                               SLEN, 3840, 1280, 1);
  rope_pack<<<dim3(SLEN / 64, NHEADS), 256, 0, stream>>>(qkvb, freqs, qp, kp, vt);
  int nseg = in_sizes[1] - 1;
  flash_attn<<<dim3(SLEN / 128, NHEADS), 256, 0, stream>>>(qp, kp, vt, cu, nseg, attn);
  gemm_bt<2><<<dim3(SLEN / 128, DMODEL / 128), 256, 0, stream>>>(attn, wprojT, b_proj, out,
                                                                 SLEN, DMODEL, 1280, 0);
}